// Round 10
// baseline (664.104 us; speedup 1.0000x reference)
//
#include <hip/hip_runtime.h>
#include <stdint.h>

// ---------- helpers ----------
typedef __attribute__((ext_vector_type(8))) short short8;   // 8 x bf16 (4 VGPRs)
typedef __attribute__((ext_vector_type(4))) float floatx4;  // MFMA accum

__device__ __forceinline__ unsigned short f2bf(float f) {
  union { float f; unsigned int u; } c; c.f = f;
  unsigned int u = c.u;
  unsigned int r = (u + 0x7fffu + ((u >> 16) & 1u)) >> 16;  // RNE
  return (unsigned short)r;
}

// async global->LDS, 16B per lane. LDS dest is wave-uniform base + lane*16.
__device__ __forceinline__ void load16_to_lds(const void* g, void* l) {
  __builtin_amdgcn_global_load_lds(
      (const __attribute__((address_space(1))) unsigned int*)g,
      (__attribute__((address_space(3))) unsigned int*)l, 16, 0, 0);
}

// ---------- merged preprocessing: x->bf16, dequant w1/w3/w2 ----------
// One launch instead of three (each launch ~10us of gap in the replayed
// graph). Flat 1D grid, job selected by block range:
//   [0, 14336)        : w1+w3 dequant  (F rows x 2 k-blocks of 1024, K=H)
//   [14336, 28672)    : w2 dequant     (H rows x 7 k-blocks of 1024, K=F)
//   [28672, 36864)    : x f32->bf16    (T*H/1024 blocks)
__global__ void preproc_kernel(const float* __restrict__ x,
                               unsigned short* __restrict__ xb,
                               const float* __restrict__ w1q,
                               const float* __restrict__ s1,
                               unsigned short* __restrict__ w1b,
                               const float* __restrict__ w3q,
                               const float* __restrict__ s3,
                               unsigned short* __restrict__ w3b,
                               const float* __restrict__ w2q,
                               const float* __restrict__ s2,
                               unsigned short* __restrict__ w2b) {
  const int bid = blockIdx.x;
  const int tid = threadIdx.x;
  if (bid < 14336) {
    // w1 + w3: K = 2048, sK = 16
    int n = bid >> 1;
    int k = (bid & 1) * 1024 + tid * 4;
    size_t idx = (size_t)n * 2048 + k;
    int sidx = (n >> 7) * 16 + (k >> 7);
    float sc1 = s1[sidx], sc3 = s3[sidx];
    float4 v1 = *(const float4*)(w1q + idx);
    float4 v3 = *(const float4*)(w3q + idx);
    ushort4 a, b;
    a.x = f2bf(v1.x * sc1); a.y = f2bf(v1.y * sc1);
    a.z = f2bf(v1.z * sc1); a.w = f2bf(v1.w * sc1);
    b.x = f2bf(v3.x * sc3); b.y = f2bf(v3.y * sc3);
    b.z = f2bf(v3.z * sc3); b.w = f2bf(v3.w * sc3);
    *(ushort4*)(w1b + idx) = a;
    *(ushort4*)(w3b + idx) = b;
  } else if (bid < 28672) {
    // w2: K = 7168, sK = 56
    int b = bid - 14336;
    int n = b / 7;
    int kb = b - n * 7;
    int k = kb * 1024 + tid * 4;
    size_t idx = (size_t)n * 7168 + k;
    float sc = s2[(n >> 7) * 56 + (k >> 7)];
    float4 v = *(const float4*)(w2q + idx);
    ushort4 o;
    o.x = f2bf(v.x * sc); o.y = f2bf(v.y * sc);
    o.z = f2bf(v.z * sc); o.w = f2bf(v.w * sc);
    *(ushort4*)(w2b + idx) = o;
  } else {
    size_t i = (size_t)(bid - 28672) * 256 + tid;  // float4 index
    float4 v = ((const float4*)x)[i];
    ushort4 o;
    o.x = f2bf(v.x); o.y = f2bf(v.y); o.z = f2bf(v.z); o.w = f2bf(v.w);
    ((ushort4*)xb)[i] = o;
  }
}

// ---------- LDS swizzle, BK=32 ----------
// Tile = 128 rows x 4 kblks (16B each). unit(row,kblk) = row*4 + (kblk ^ (row&3)).
// Balanced over bank-groups for both staging and fragment reads (8 lanes per
// 4-bank group = the b128 service floor) -> expect ~0 conflicts.

// ---------- merged dual GEMM + silu, double-buffered K-loop ----------
// R10: BK=32 double-buffer, ONE barrier per iteration. Loads for iter k+1
// are issued right after barrier(k), so at barrier(k+1) they have aged one
// full compute phase -> the vmcnt(0)-before-barrier drain (the structural
// ~20% stall of the 2-barrier loop) is mostly hidden. Buffer safety with a
// single barrier: readers of buf[1-c] (compute k-1) finished before
// barrier(k); writes into buf[1-c] are issued after it. LDS 2*3*8 = 48 KB
// -> still 2 blocks/CU (reg-limited), preserving cross-block overlap.
__global__ __launch_bounds__(512, 4) void dual_gemm_silu(
    const unsigned short* __restrict__ A,   // [M,K] bf16 (x)
    const unsigned short* __restrict__ B1,  // [N,K] bf16 (w1)
    const unsigned short* __restrict__ B3,  // [N,K] bf16 (w3)
    unsigned short* __restrict__ C,         // [M,N] bf16 fused
    int M, int N, int K) {
  __shared__ unsigned short As[2][128 * 32];   // 2 x 8 KB
  __shared__ unsigned short B1s[2][128 * 32];
  __shared__ unsigned short B3s[2][128 * 32];

  const int tid = threadIdx.x;
  const int lane = tid & 63;
  const int wave = tid >> 6;      // 0..7
  const int wm = wave >> 2;       // 0..1  (M 64-half)
  const int wn = wave & 3;        // 0..3  (N 32-quarter)
  const int m0 = blockIdx.y * 128, n0 = blockIdx.x * 128;

  // staging: 512 units; thread t -> unit t (row = t>>2, kblk swizzled)
  const int sr = tid >> 2;
  const int sc = ((tid & 3) ^ (sr & 3)) * 8;
  const int ldst = tid * 8;
  const unsigned short* ag = A + (size_t)(m0 + sr) * K + sc;
  const unsigned short* b1g = B1 + (size_t)(n0 + sr) * K + sc;
  const unsigned short* b3g = B3 + (size_t)(n0 + sr) * K + sc;

  const int q = lane >> 4;        // kblk 0..3, out-row base q*4
  const int r16 = lane & 15;
  const int rq = r16 & 3;         // row&3 for all fragment rows

  floatx4 acc_g[4][2], acc_u[4][2];
#pragma unroll
  for (int i = 0; i < 4; i++)
#pragma unroll
    for (int j = 0; j < 2; j++) {
      acc_g[i][j] = (floatx4){0.f, 0.f, 0.f, 0.f};
      acc_u[i][j] = (floatx4){0.f, 0.f, 0.f, 0.f};
    }

  // fragment LDS offsets (ushort index), fixed per thread
  int aoffs[4], boffs[2];
#pragma unroll
  for (int t = 0; t < 4; t++)
    aoffs[t] = ((wm * 64 + t * 16 + r16) * 4 + (q ^ rq)) * 8;
#pragma unroll
  for (int j = 0; j < 2; j++)
    boffs[j] = ((wn * 32 + j * 16 + r16) * 4 + (q ^ rq)) * 8;

  const int nIter = K >> 5;   // 64

  // prologue: stage tile 0 into buffer 0
  load16_to_lds(ag, &As[0][ldst]);
  load16_to_lds(b1g, &B1s[0][ldst]);
  load16_to_lds(b3g, &B3s[0][ldst]);

  for (int it = 0; it < nIter; ++it) {
    __syncthreads();            // drains loads for buf c (issued last iter)
    const int c = it & 1;
    if (it + 1 < nIter) {
      const int k0 = (it + 1) << 5;
      const int nc = c ^ 1;
      load16_to_lds(ag + k0, &As[nc][ldst]);
      load16_to_lds(b1g + k0, &B1s[nc][ldst]);
      load16_to_lds(b3g + k0, &B3s[nc][ldst]);
    }
    short8 a[4], b1v[2], b3v[2];
#pragma unroll
    for (int t = 0; t < 4; t++)
      a[t] = *(const short8*)&As[c][aoffs[t]];
#pragma unroll
    for (int j = 0; j < 2; j++) {
      b1v[j] = *(const short8*)&B1s[c][boffs[j]];
      b3v[j] = *(const short8*)&B3s[c][boffs[j]];
    }
#pragma unroll
    for (int i = 0; i < 4; i++)
#pragma unroll
      for (int j = 0; j < 2; j++) {
        acc_g[i][j] = __builtin_amdgcn_mfma_f32_16x16x32_bf16(
            a[i], b1v[j], acc_g[i][j], 0, 0, 0);
        acc_u[i][j] = __builtin_amdgcn_mfma_f32_16x16x32_bf16(
            a[i], b3v[j], acc_u[i][j], 0, 0, 0);
      }
  }

  // epilogue: D col = lane&15, row = quad*4 + reg (m89/m91-verified)
#pragma unroll
  for (int i = 0; i < 4; i++) {
    int row0 = m0 + wm * 64 + i * 16 + q * 4;
#pragma unroll
    for (int j = 0; j < 2; j++) {
      int col = n0 + wn * 32 + j * 16 + r16;
#pragma unroll
      for (int rr = 0; rr < 4; rr++) {
        float gv = acc_g[i][j][rr];
        float uv = acc_u[i][j][rr];
        float sv = gv / (1.f + __expf(-gv)) * uv;
        C[(size_t)(row0 + rr) * N + col] = f2bf(sv);
      }
    }
  }
}

// ---------- GEMM3 split-K=2, double-buffered ----------
// 4 waves (2x2), wave-tile 64x64, BK=32 dbuf (2*2*8 = 32 KB LDS).
// launch_bounds(256,3): ~134 regs/wave -> 3 waves/EU -> 3 blocks/CU.
// Epilogue unsafeAtomicAdd into pre-zeroed d_out (2 commutative adds).
__global__ __launch_bounds__(256, 3) void gemm_nt_f32_sk(
    const unsigned short* __restrict__ A,  // [M,K] bf16
    const unsigned short* __restrict__ B,  // [N,K] bf16
    float* __restrict__ C,                 // [M,N] fp32 (pre-zeroed)
    int M, int N, int K) {
  __shared__ unsigned short As[2][128 * 32];
  __shared__ unsigned short Bs[2][128 * 32];

  const int tid = threadIdx.x;
  const int lane = tid & 63;
  const int wave = tid >> 6;
  const int wm = wave >> 1;       // 0..1
  const int wn = wave & 1;        // 0..1
  const int m0 = blockIdx.y * 128, n0 = blockIdx.x * 128;
  const int kbase = blockIdx.z * (K >> 1);
  const int nIter = K >> 6;       // (K/2)/32 = 112

  // staging: 512 units; thread t -> units t and t+256
  int soff[2], sdst[2];
#pragma unroll
  for (int p = 0; p < 2; p++) {
    int u = tid + 256 * p;
    int r = u >> 2;
    int c = ((u & 3) ^ (r & 3)) * 8;
    soff[p] = r * K + c;
    sdst[p] = u * 8;
  }

  const int q = lane >> 4;
  const int r16 = lane & 15;
  const int rq = r16 & 3;

  floatx4 acc[4][4];
#pragma unroll
  for (int i = 0; i < 4; i++)
#pragma unroll
    for (int j = 0; j < 4; j++) acc[i][j] = (floatx4){0.f, 0.f, 0.f, 0.f};

  int aoffs[4], boffs[4];
#pragma unroll
  for (int t = 0; t < 4; t++) {
    aoffs[t] = ((wm * 64 + t * 16 + r16) * 4 + (q ^ rq)) * 8;
    boffs[t] = ((wn * 64 + t * 16 + r16) * 4 + (q ^ rq)) * 8;
  }

  const unsigned short* Abase = A + (size_t)m0 * K + kbase;
  const unsigned short* Bbase = B + (size_t)n0 * K + kbase;

  // prologue
#pragma unroll
  for (int p = 0; p < 2; p++) {
    load16_to_lds(Abase + soff[p], &As[0][sdst[p]]);
    load16_to_lds(Bbase + soff[p], &Bs[0][sdst[p]]);
  }

  for (int it = 0; it < nIter; ++it) {
    __syncthreads();
    const int c = it & 1;
    if (it + 1 < nIter) {
      const int k0 = (it + 1) << 5;
      const int nc = c ^ 1;
#pragma unroll
      for (int p = 0; p < 2; p++) {
        load16_to_lds(Abase + soff[p] + k0, &As[nc][sdst[p]]);
        load16_to_lds(Bbase + soff[p] + k0, &Bs[nc][sdst[p]]);
      }
    }
    short8 a[4], b[4];
#pragma unroll
    for (int t = 0; t < 4; t++) {
      a[t] = *(const short8*)&As[c][aoffs[t]];
      b[t] = *(const short8*)&Bs[c][boffs[t]];
    }
#pragma unroll
    for (int i = 0; i < 4; i++)
#pragma unroll
      for (int j = 0; j < 4; j++)
        acc[i][j] = __builtin_amdgcn_mfma_f32_16x16x32_bf16(
            a[i], b[j], acc[i][j], 0, 0, 0);
  }

#pragma unroll
  for (int i = 0; i < 4; i++) {
    int row0 = m0 + wm * 64 + i * 16 + q * 4;
#pragma unroll
    for (int j = 0; j < 4; j++) {
      int col = n0 + wn * 64 + j * 16 + r16;
#pragma unroll
      for (int rr = 0; rr < 4; rr++)
        unsafeAtomicAdd(&C[(size_t)(row0 + rr) * N + col], acc[i][j][rr]);
    }
  }
}

// ---------- launch ----------
extern "C" void kernel_launch(void* const* d_in, const int* in_sizes, int n_in,
                              void* d_out, int out_size, void* d_ws, size_t ws_size,
                              hipStream_t stream) {
  const float* x = (const float*)d_in[0];
  const float* w1q = (const float*)d_in[1];
  const float* w1s = (const float*)d_in[2];
  const float* w3q = (const float*)d_in[3];
  const float* w3s = (const float*)d_in[4];
  const float* w2q = (const float*)d_in[5];
  const float* w2s = (const float*)d_in[6];

  const int T = 4096, H = 2048, F = 7168;

  char* ws = (char*)d_ws;
  unsigned short* xb  = (unsigned short*)ws;  ws += (size_t)T * H * 2;   // 16.8 MB
  unsigned short* w1b = (unsigned short*)ws;  ws += (size_t)F * H * 2;   // 29.4 MB
  unsigned short* w3b = (unsigned short*)ws;  ws += (size_t)F * H * 2;   // 29.4 MB
  unsigned short* w2b = (unsigned short*)ws;  ws += (size_t)H * F * 2;   // 29.4 MB
  unsigned short* g   = (unsigned short*)ws;  ws += (size_t)T * F * 2;   // 58.7 MB

  // one merged preprocessing launch (x convert + 3 dequants)
  preproc_kernel<<<36864, 256, 0, stream>>>(
      x, xb, w1q, w1s, w1b, w3q, w3s, w3b, w2q, w2s, w2b);

  // g = silu(x @ w1^T) * (x @ w3^T)
  dual_gemm_silu<<<dim3(F / 128, T / 128), 512, 0, stream>>>(xb, w1b, w3b, g, T, F, H);

  // out = g @ w2^T  (fp32, split-K=2 accumulated via atomics)
  hipMemsetAsync(d_out, 0, (size_t)T * H * 4, stream);
  gemm_nt_f32_sk<<<dim3(H / 128, T / 128, 2), 256, 0, stream>>>(
      g, w2b, (float*)d_out, T, H, F);
}